// Round 9
// baseline (160.311 us; speedup 1.0000x reference)
//
#include <hip/hip_runtime.h>
#include <stdint.h>

// Problem constants
#define BB 4
#define LL 4096
#define CC 1024
#define HH 16
#define DD 64
#define MTOT (BB*LL)      // 16384
#define NQK 2048          // q(1024) + k(1024) columns

typedef __attribute__((ext_vector_type(4))) float f32x4;
typedef __attribute__((ext_vector_type(8))) short bf16x8;
typedef __attribute__((ext_vector_type(4))) unsigned short u16x4;
typedef unsigned short u16;

__device__ __forceinline__ u16 f2bf(float f) {
    union { float f; uint32_t u; } v; v.f = f;
    uint32_t r = v.u + 0x7fffu + ((v.u >> 16) & 1u);   // RNE
    return (u16)(r >> 16);
}
__device__ __forceinline__ float elu1(float s) {
    return s > 0.f ? s + 1.f : __expf(s);
}

// ---------------- cast x (fp32 -> bf16) ----------------
__global__ __launch_bounds__(256) void cast_x_kernel(const float* __restrict__ x,
                                                     u16* __restrict__ xb, int n4) {
    int idx = blockIdx.x * blockDim.x + threadIdx.x;
    int stride = gridDim.x * blockDim.x;
    const f32x4* x4 = (const f32x4*)x;
    u16x4* o4 = (u16x4*)xb;
    for (int i = idx; i < n4; i += stride) {
        f32x4 v = x4[i];
        u16x4 o;
        o.x = f2bf(v.x); o.y = f2bf(v.y); o.z = f2bf(v.z); o.w = f2bf(v.w);
        o4[i] = o;
    }
}

// ---------------- Wvs^T: wvst[h][k] = bf16( sum_d W_qkv[k][2048 + h*64 + d] ) ----------------
__global__ __launch_bounds__(256) void wsum_kernel(const float* __restrict__ Wqkv,
                                                   u16* __restrict__ wvst) {
    int k = blockIdx.x;              // 0..1023
    int t = threadIdx.x;             // 0..255, each loads 4 consecutive v-cols
    const f32x4* row = (const f32x4*)(Wqkv + (size_t)k * 3072 + 2048);
    f32x4 v = row[t];
    float s = v.x + v.y + v.z + v.w;
    s += __shfl_xor(s, 1); s += __shfl_xor(s, 2);
    s += __shfl_xor(s, 4); s += __shfl_xor(s, 8);
    if ((t & 15) == 0) {
        int h = t >> 4;              // 0..15
        wvst[h * 1024 + k] = f2bf(s);
    }
}

// ---------------- transpose+cast W_qkv cols 0..2047 -> wqkt[n][k] bf16 ----------------
__global__ void trans_wqk_kernel(const float* __restrict__ Wqkv, u16* __restrict__ wqkt) {
    __shared__ float tile[32][33];
    int n0 = blockIdx.x * 32;        // 64 blocks
    int k0 = blockIdx.y * 32;        // 32 blocks
    int tx = threadIdx.x;            // 0..31
    int ty = threadIdx.y;            // 0..7
    #pragma unroll
    for (int i = 0; i < 32; i += 8)
        tile[ty + i][tx] = Wqkv[(size_t)(k0 + ty + i) * 3072 + n0 + tx];
    __syncthreads();
    #pragma unroll
    for (int i = 0; i < 32; i += 8)
        wqkt[(size_t)(n0 + ty + i) * 1024 + k0 + tx] = f2bf(tile[tx][ty + i]);
}

// ---------------- vsum[row][h] = sum_k x[row,k] * Wvs[k,h]  (tiny MFMA GEMM) ----------------
__global__ __launch_bounds__(256) void vsum_kernel(const u16* __restrict__ xb,
                                                   const u16* __restrict__ wvst,
                                                   float* __restrict__ vsum) {
    int lane = threadIdx.x & 63;
    int w = threadIdx.x >> 6;
    int m0 = blockIdx.x * 64 + w * 16;          // 256 blocks * 4 waves * 16 rows = 16384
    int r = lane & 15, g = lane >> 4;
    f32x4 acc = {0.f, 0.f, 0.f, 0.f};
    const bf16x8* ap = (const bf16x8*)(xb + (size_t)(m0 + r) * 1024 + g * 8);
    const bf16x8* bp = (const bf16x8*)(wvst + (size_t)r * 1024 + g * 8);
    #pragma unroll 4
    for (int kt = 0; kt < 1024; kt += 32) {
        bf16x8 a = ap[kt >> 3];
        bf16x8 b = bp[kt >> 3];
        acc = __builtin_amdgcn_mfma_f32_16x16x32_bf16(a, b, acc, 0, 0, 0);
    }
    #pragma unroll
    for (int ri = 0; ri < 4; ++ri)
        vsum[(size_t)(m0 + g * 4 + ri) * 16 + r] = acc[ri];
}

// ---------------- main GEMM: 128x128 tile, BK=32, 2 waves x (128x64 wave-tile) ----------------
// Round-9 change: wave-tile 64x64 -> 128x64. LDS-read intensity 2.0 -> 2.67
// (12 ds_read_b128 per 32 MFMA instead of 8 per 16) -- round 8 was LDS-read-bound
// (LDS ~640 cyc/block-step vs MFMA 310). 128 threads/block, acc 128 + frags 48
// regs fits __launch_bounds__(128,2) 256-reg cap; 4 blocks/CU (8 waves) for TLP.
__global__ __launch_bounds__(128, 2) void gemm_qk_kernel(const u16* __restrict__ A,
                                                         const u16* __restrict__ Bt,
                                                         const float* __restrict__ vsum,
                                                         float* __restrict__ qsum,
                                                         float* __restrict__ kvsum) {
    __shared__ u16 As[2][128 * 32];
    __shared__ u16 Bs[2][128 * 32];
    const int tid = threadIdx.x;     // 0..127
    const int lane = tid & 63;
    const int wv = tid >> 6;         // 0..1 (N half of the 128-col tile)
    const int r = lane & 15;
    const int gq = lane >> 4;

    // T1: 2048 blocks -> each XCD gets a contiguous 256-block chunk
    const int wg = blockIdx.x;
    const int s = (wg & 7) * 256 + (wg >> 3);
    const int bx = s >> 4;           // 0..127 (M)
    const int by = s & 15;           // 0..15  (N)
    const int m0 = bx * 128;
    const int n0 = by * 128;

    // staging: GL chunk i covers rows i*32 + (tid>>2), slot tid&3; inverse-swizzled col.
    // (row>>2)&3 == (tid>>4)&3 for all i (i*8 = 0 mod 4), so scol is i-independent.
    const int srow = tid >> 2;                              // 0..31
    const int scol = ((tid & 3) ^ ((tid >> 4) & 3)) * 8;
    const u16* aSrc = A + (size_t)(m0 + srow) * 1024 + scol;
    const u16* bSrc = Bt + (size_t)(n0 + srow) * 1024 + scol;
    const int t8 = tid * 8;

#define GL(gp, lp) __builtin_amdgcn_global_load_lds(                                  \
        (const __attribute__((address_space(1))) void*)(gp),                          \
        (__attribute__((address_space(3))) void*)(lp), 16, 0, 0)
#define STAGE(D, KT) do {                                                             \
        _Pragma("unroll")                                                             \
        for (int i = 0; i < 4; ++i)                                                   \
            GL(aSrc + (size_t)i * 32 * 1024 + (KT), &As[D][i * 1024 + t8]);           \
        _Pragma("unroll")                                                             \
        for (int i = 0; i < 4; ++i)                                                   \
            GL(bSrc + (size_t)i * 32 * 1024 + (KT), &Bs[D][i * 1024 + t8]);           \
    } while (0)

    f32x4 acc[8][4];                 // [mi: 16-row group of 128][ni: 16-col group of 64]
    #pragma unroll
    for (int i = 0; i < 8; ++i)
        #pragma unroll
        for (int j = 0; j < 4; ++j)
            acc[i][j] = (f32x4){0.f, 0.f, 0.f, 0.f};

    const int sk = (gq ^ ((r >> 2) & 3)) * 8;   // swizzled read slot (row>>2)&3 == (r>>2)&3

    // prologue
    STAGE(0, 0);
    asm volatile("s_waitcnt vmcnt(0)" ::: "memory");
    __builtin_amdgcn_s_barrier();

#define BODY(T, CUR) do {                                                             \
        if ((T) + 1 < 32) STAGE((CUR) ^ 1, ((T) + 1) * 32);                           \
        bf16x8 a[8], b[4];                                                            \
        const u16* ap = &As[CUR][r * 32 + sk];                                        \
        const u16* bp = &Bs[CUR][(wv * 64 + r) * 32 + sk];                            \
        _Pragma("unroll")                                                             \
        for (int mi = 0; mi < 8; ++mi) a[mi] = *(const bf16x8*)(ap + mi * 512);       \
        _Pragma("unroll")                                                             \
        for (int ni = 0; ni < 4; ++ni) b[ni] = *(const bf16x8*)(bp + ni * 512);       \
        __builtin_amdgcn_s_setprio(1);                                                \
        _Pragma("unroll")                                                             \
        for (int mi = 0; mi < 8; ++mi)                                                \
            _Pragma("unroll")                                                         \
            for (int ni = 0; ni < 4; ++ni)                                            \
                acc[mi][ni] = __builtin_amdgcn_mfma_f32_16x16x32_bf16(                \
                    a[mi], b[ni], acc[mi][ni], 0, 0, 0);                              \
        __builtin_amdgcn_s_setprio(0);                                                \
        asm volatile("s_waitcnt vmcnt(0)" ::: "memory");                              \
        __builtin_amdgcn_s_barrier();                                                 \
    } while (0)

    for (int t = 0; t < 32; t += 2) {
        BODY(t, 0);
        BODY(t + 1, 1);
    }
#undef BODY
#undef STAGE
#undef GL

    // epilogue. Rows: m0 + mi*16 + gq*4 + rr; cols: n0 + wv*64 + ni*16 + r.
    // Wave's 64 cols = exactly one head.
    if (by < 8) {
        const int h = by * 2 + wv;
        #pragma unroll
        for (int mi = 0; mi < 8; ++mi)
            #pragma unroll
            for (int rr = 0; rr < 4; ++rr) {
                float sv = elu1(acc[mi][0][rr]) + elu1(acc[mi][1][rr]) +
                           elu1(acc[mi][2][rr]) + elu1(acc[mi][3][rr]);
                sv += __shfl_xor(sv, 1); sv += __shfl_xor(sv, 2);
                sv += __shfl_xor(sv, 4); sv += __shfl_xor(sv, 8);
                if (r == 0)
                    qsum[(size_t)(m0 + mi * 16 + gq * 4 + rr) * 16 + h] = sv;
            }
    } else {
        const int h = (by - 8) * 2 + wv;
        const int b = m0 >> 12;
        float kvp[4] = {0.f, 0.f, 0.f, 0.f};
        #pragma unroll
        for (int mi = 0; mi < 8; ++mi)
            #pragma unroll
            for (int rr = 0; rr < 4; ++rr) {
                const int row = m0 + mi * 16 + gq * 4 + rr;
                const float vs = vsum[(size_t)row * 16 + h];
                #pragma unroll
                for (int nj = 0; nj < 4; ++nj)
                    kvp[nj] += elu1(acc[mi][nj][rr]) * vs;
            }
        #pragma unroll
        for (int nj = 0; nj < 4; ++nj) {
            kvp[nj] += __shfl_xor(kvp[nj], 16);
            kvp[nj] += __shfl_xor(kvp[nj], 32);
        }
        if (gq == 0) {
            #pragma unroll
            for (int nj = 0; nj < 4; ++nj)
                atomicAdd(&kvsum[((size_t)b * 16 + h) * 64 + nj * 16 + r], kvp[nj]);
        }
    }
}

// ---------------- Wkv[b][h][c] = sum_d kvrow[b][h][d] * W_proj[h*64+d][c] ----------------
__global__ __launch_bounds__(256) void wkv_kernel(const float* __restrict__ kvsum,
                                                  const float* __restrict__ Wproj,
                                                  float* __restrict__ wkv) {
    __shared__ float kv[64];
    const int bh = blockIdx.y;                     // 0..63
    const int c = blockIdx.x * 256 + threadIdx.x;  // 0..1023
    if (threadIdx.x < 64) kv[threadIdx.x] = kvsum[bh * 64 + threadIdx.x];
    __syncthreads();
    const int h = bh & 15;
    float s = 0.f;
    #pragma unroll 8
    for (int d = 0; d < 64; ++d)
        s += kv[d] * Wproj[(size_t)(h * 64 + d) * 1024 + c];
    wkv[(size_t)bh * 1024 + c] = s;
}

// ---------------- y[row][c] = b_proj[c] + sum_h qsum[row][h] * Wkv[b][h][c] ----------------
__global__ __launch_bounds__(256) void final_kernel(const float* __restrict__ qsum,
                                                    const float* __restrict__ wkv,
                                                    const float* __restrict__ bproj,
                                                    float* __restrict__ y) {
    __shared__ float qs[4][16];
    const int r0 = blockIdx.x * 4;                 // 4096 blocks, 4 rows each
    const int t = threadIdx.x;
    if (t < 64) qs[t >> 4][t & 15] = qsum[(size_t)(r0 + (t >> 4)) * 16 + (t & 15)];
    __syncthreads();
    const int b = r0 >> 12;
    const f32x4* wk4 = (const f32x4*)(wkv + (size_t)b * 16 * 1024);
    f32x4 bp = ((const f32x4*)bproj)[t];
    f32x4 a0 = bp, a1 = bp, a2 = bp, a3 = bp;
    #pragma unroll
    for (int h = 0; h < 16; ++h) {
        f32x4 w = wk4[h * 256 + t];
        a0 += qs[0][h] * w;
        a1 += qs[1][h] * w;
        a2 += qs[2][h] * w;
        a3 += qs[3][h] * w;
    }
    f32x4* y4 = (f32x4*)y;
    y4[(size_t)(r0 + 0) * 256 + t] = a0;
    y4[(size_t)(r0 + 1) * 256 + t] = a1;
    y4[(size_t)(r0 + 2) * 256 + t] = a2;
    y4[(size_t)(r0 + 3) * 256 + t] = a3;
}

extern "C" void kernel_launch(void* const* d_in, const int* in_sizes, int n_in,
                              void* d_out, int out_size, void* d_ws, size_t ws_size,
                              hipStream_t stream) {
    const float* x     = (const float*)d_in[0];   // [4,4096,1024]
    const float* Wqkv  = (const float*)d_in[1];   // [1024,3072]
    const float* Wproj = (const float*)d_in[2];   // [1024,1024]
    const float* bproj = (const float*)d_in[3];   // [1024]
    float* y = (float*)d_out;                     // [4,4096,1024]

    char* ws = (char*)d_ws;
    u16*   xb    = (u16*)(ws);                    // 16384*1024*2 = 33554432
    u16*   wqkt  = (u16*)(ws + 33554432);         // 2048*1024*2  =  4194304
    u16*   wvst  = (u16*)(ws + 37748736);         // 16*1024*2    =    32768
    float* vsum  = (float*)(ws + 37781504);       // 16384*16*4   =  1048576
    float* qsum  = (float*)(ws + 38830080);       // 16384*16*4   =  1048576
    float* kvsum = (float*)(ws + 39878656);       // 4*16*64*4    =    16384
    float* wkv   = (float*)(ws + 39895040);       // 4*16*1024*4  =   262144
    // total 40157184 bytes (~38.3 MiB)

    hipMemsetAsync(kvsum, 0, 4096 * sizeof(float), stream);

    cast_x_kernel<<<4096, 256, 0, stream>>>(x, xb, (MTOT * CC) / 4);
    wsum_kernel<<<1024, 256, 0, stream>>>(Wqkv, wvst);
    trans_wqk_kernel<<<dim3(64, 32), dim3(32, 8), 0, stream>>>(Wqkv, wqkt);
    vsum_kernel<<<256, 256, 0, stream>>>(xb, wvst, vsum);
    gemm_qk_kernel<<<2048, 128, 0, stream>>>(xb, wqkt, vsum, qsum, kvsum);
    wkv_kernel<<<dim3(4, 64), 256, 0, stream>>>(kvsum, Wproj, wkv);
    final_kernel<<<4096, 256, 0, stream>>>(qsum, wkv, bproj, y);
}

// Round 10
// 143.845 us; speedup vs baseline: 1.1145x; 1.1145x over previous
//
#include <hip/hip_runtime.h>
#include <stdint.h>

// Problem constants
#define BB 4
#define LL 4096
#define CC 1024
#define HH 16
#define DD 64
#define MTOT (BB*LL)      // 16384
#define NQK 2048          // q(1024) + k(1024) columns

typedef __attribute__((ext_vector_type(4))) float f32x4;
typedef __attribute__((ext_vector_type(8))) short bf16x8;
typedef __attribute__((ext_vector_type(4))) unsigned short u16x4;
typedef unsigned short u16;

__device__ __forceinline__ u16 f2bf(float f) {
    union { float f; uint32_t u; } v; v.f = f;
    uint32_t r = v.u + 0x7fffu + ((v.u >> 16) & 1u);   // RNE
    return (u16)(r >> 16);
}
__device__ __forceinline__ float elu1(float s) {
    return s > 0.f ? s + 1.f : __expf(s);
}

// ---------------- cast x (fp32 -> bf16) ----------------
__global__ __launch_bounds__(256) void cast_x_kernel(const float* __restrict__ x,
                                                     u16* __restrict__ xb, int n4) {
    int idx = blockIdx.x * blockDim.x + threadIdx.x;
    int stride = gridDim.x * blockDim.x;
    const f32x4* x4 = (const f32x4*)x;
    u16x4* o4 = (u16x4*)xb;
    for (int i = idx; i < n4; i += stride) {
        f32x4 v = x4[i];
        u16x4 o;
        o.x = f2bf(v.x); o.y = f2bf(v.y); o.z = f2bf(v.z); o.w = f2bf(v.w);
        o4[i] = o;
    }
}

// ---------------- Wvs^T: wvst[h][k] = bf16( sum_d W_qkv[k][2048 + h*64 + d] ) ----------------
__global__ __launch_bounds__(256) void wsum_kernel(const float* __restrict__ Wqkv,
                                                   u16* __restrict__ wvst) {
    int k = blockIdx.x;              // 0..1023
    int t = threadIdx.x;             // 0..255, each loads 4 consecutive v-cols
    const f32x4* row = (const f32x4*)(Wqkv + (size_t)k * 3072 + 2048);
    f32x4 v = row[t];
    float s = v.x + v.y + v.z + v.w;
    s += __shfl_xor(s, 1); s += __shfl_xor(s, 2);
    s += __shfl_xor(s, 4); s += __shfl_xor(s, 8);
    if ((t & 15) == 0) {
        int h = t >> 4;              // 0..15
        wvst[h * 1024 + k] = f2bf(s);
    }
}

// ---------------- transpose+cast W_qkv cols 0..2047 -> wqkt[n][k] bf16 ----------------
__global__ void trans_wqk_kernel(const float* __restrict__ Wqkv, u16* __restrict__ wqkt) {
    __shared__ float tile[32][33];
    int n0 = blockIdx.x * 32;        // 64 blocks
    int k0 = blockIdx.y * 32;        // 32 blocks
    int tx = threadIdx.x;            // 0..31
    int ty = threadIdx.y;            // 0..7
    #pragma unroll
    for (int i = 0; i < 32; i += 8)
        tile[ty + i][tx] = Wqkv[(size_t)(k0 + ty + i) * 3072 + n0 + tx];
    __syncthreads();
    #pragma unroll
    for (int i = 0; i < 32; i += 8)
        wqkt[(size_t)(n0 + ty + i) * 1024 + k0 + tx] = f2bf(tile[tx][ty + i]);
}

// ---------------- vsum[row][h] = sum_k x[row,k] * Wvs[k,h]  (tiny MFMA GEMM) ----------------
__global__ __launch_bounds__(256) void vsum_kernel(const u16* __restrict__ xb,
                                                   const u16* __restrict__ wvst,
                                                   float* __restrict__ vsum) {
    int lane = threadIdx.x & 63;
    int w = threadIdx.x >> 6;
    int m0 = blockIdx.x * 64 + w * 16;          // 256 blocks * 4 waves * 16 rows = 16384
    int r = lane & 15, g = lane >> 4;
    f32x4 acc = {0.f, 0.f, 0.f, 0.f};
    const bf16x8* ap = (const bf16x8*)(xb + (size_t)(m0 + r) * 1024 + g * 8);
    const bf16x8* bp = (const bf16x8*)(wvst + (size_t)r * 1024 + g * 8);
    #pragma unroll 4
    for (int kt = 0; kt < 1024; kt += 32) {
        bf16x8 a = ap[kt >> 3];
        bf16x8 b = bp[kt >> 3];
        acc = __builtin_amdgcn_mfma_f32_16x16x32_bf16(a, b, acc, 0, 0, 0);
    }
    #pragma unroll
    for (int ri = 0; ri < 4; ++ri)
        vsum[(size_t)(m0 + g * 4 + ri) * 16 + r] = acc[ri];
}

// ---------------- main GEMM: 128x128, BK=32, 4 waves, 3 blocks/CU, TRIPLE buffer ----------------
// Round-10 change vs round 8 (single variable): 2-ahead staging + counted vmcnt(8).
// Body t stages tile t+2, reads tile t, waits vmcnt(8) = "tile t+1 landed" while
// tile t+2's 8 loads stay in flight ACROSS the barrier (T4: never drain to 0).
// The waited-on loads were issued a full body (~900cy) earlier -> wait is ~free.
// LDS 3 x 16KB = 48KB -> still 3 blocks/CU at __launch_bounds__(256,3).
__global__ __launch_bounds__(256, 3) void gemm_qk_kernel(const u16* __restrict__ A,
                                                         const u16* __restrict__ Bt,
                                                         const float* __restrict__ vsum,
                                                         float* __restrict__ qsum,
                                                         float* __restrict__ kvsum) {
    __shared__ u16 As[3][128 * 32];
    __shared__ u16 Bs[3][128 * 32];
    const int tid = threadIdx.x;
    const int lane = tid & 63;
    const int w = tid >> 6;          // 0..3
    const int wm = w >> 1;           // 0..1
    const int wn = w & 1;            // 0..1
    const int r = lane & 15;
    const int gq = lane >> 4;

    // T1: 2048 blocks -> each XCD gets a contiguous 256-block chunk (16 bx stripes)
    const int wg = blockIdx.x;
    const int s = (wg & 7) * 256 + (wg >> 3);
    const int bx = s >> 4;           // 0..127 (M)
    const int by = s & 15;           // 0..15  (N)
    const int m0 = bx * 128;
    const int n0 = by * 128;

    // staging: thread -> (row = tid>>2, phys slot p = tid&3); inverse-swizzled global col
    const int srow = tid >> 2;                            // 0..63
    const int scol = ((tid & 3) ^ ((srow >> 2) & 3)) * 8; // logical 8-elem chunk
    const u16* aSrc = A + (size_t)(m0 + srow) * 1024 + scol;
    const u16* bSrc = Bt + (size_t)(n0 + srow) * 1024 + scol;
    const int t8 = tid * 8;

#define GL(gp, lp) __builtin_amdgcn_global_load_lds(                                  \
        (const __attribute__((address_space(1))) void*)(gp),                          \
        (__attribute__((address_space(3))) void*)(lp), 16, 0, 0)
#define STAGE(D, KT) do {                                                             \
        GL(aSrc + (KT), &As[D][t8]);                                                  \
        GL(aSrc + 64 * 1024 + (KT), &As[D][t8 + 2048]);                               \
        GL(bSrc + (KT), &Bs[D][t8]);                                                  \
        GL(bSrc + 64 * 1024 + (KT), &Bs[D][t8 + 2048]);                               \
    } while (0)

    f32x4 acc[4][4];
    #pragma unroll
    for (int i = 0; i < 4; ++i)
        #pragma unroll
        for (int j = 0; j < 4; ++j)
            acc[i][j] = (f32x4){0.f, 0.f, 0.f, 0.f};

    const int sk = (gq ^ ((r >> 2) & 3)) * 8;   // swizzled read slot

    // prologue: stage tiles 0 and 1; require tile 0 landed (vmcnt(8) leaves tile 1 in flight)
    STAGE(0, 0);
    STAGE(1, 32);
    asm volatile("s_waitcnt vmcnt(8)" ::: "memory");
    __builtin_amdgcn_s_barrier();

#define BODY(T, CUR, STG) do {                                                        \
        if ((T) + 2 < 32) STAGE(STG, ((T) + 2) * 32);                                 \
        bf16x8 a[4], b[4];                                                            \
        const u16* ap = &As[CUR][(wm * 64 + r) * 32 + sk];                            \
        const u16* bp = &Bs[CUR][(wn * 64 + r) * 32 + sk];                            \
        _Pragma("unroll")                                                             \
        for (int mi = 0; mi < 4; ++mi) a[mi] = *(const bf16x8*)(ap + mi * 512);       \
        _Pragma("unroll")                                                             \
        for (int ni = 0; ni < 4; ++ni) b[ni] = *(const bf16x8*)(bp + ni * 512);       \
        __builtin_amdgcn_s_setprio(1);                                                \
        _Pragma("unroll")                                                             \
        for (int mi = 0; mi < 4; ++mi)                                                \
            _Pragma("unroll")                                                         \
            for (int ni = 0; ni < 4; ++ni)                                            \
                acc[mi][ni] = __builtin_amdgcn_mfma_f32_16x16x32_bf16(                \
                    a[mi], b[ni], acc[mi][ni], 0, 0, 0);                              \
        __builtin_amdgcn_s_setprio(0);                                                \
        if ((T) + 2 < 32)      { asm volatile("s_waitcnt vmcnt(8)" ::: "memory"); }   \
        else if ((T) + 1 < 32) { asm volatile("s_waitcnt vmcnt(0)" ::: "memory"); }   \
        __builtin_amdgcn_s_barrier();                                                 \
    } while (0)

    for (int t = 0; t < 30; t += 3) {
        BODY(t, 0, 2);
        BODY(t + 1, 1, 0);
        BODY(t + 2, 2, 1);
    }
    BODY(30, 0, 2);
    BODY(31, 1, 0);
#undef BODY
#undef STAGE
#undef GL

    // epilogue. Wave rows: m0 + wm*64 + mi*16 + gq*4 + rr; cols: n0 + wn*64 + ni*16 + r.
    // Wave's 64 cols = exactly one head.
    if (by < 8) {
        const int h = by * 2 + wn;
        #pragma unroll
        for (int mi = 0; mi < 4; ++mi)
            #pragma unroll
            for (int rr = 0; rr < 4; ++rr) {
                float sv = elu1(acc[mi][0][rr]) + elu1(acc[mi][1][rr]) +
                           elu1(acc[mi][2][rr]) + elu1(acc[mi][3][rr]);
                sv += __shfl_xor(sv, 1); sv += __shfl_xor(sv, 2);
                sv += __shfl_xor(sv, 4); sv += __shfl_xor(sv, 8);
                if (r == 0)
                    qsum[(size_t)(m0 + wm * 64 + mi * 16 + gq * 4 + rr) * 16 + h] = sv;
            }
    } else {
        const int h = (by - 8) * 2 + wn;
        const int b = m0 >> 12;
        float kvp[4] = {0.f, 0.f, 0.f, 0.f};
        #pragma unroll
        for (int mi = 0; mi < 4; ++mi)
            #pragma unroll
            for (int rr = 0; rr < 4; ++rr) {
                const int row = m0 + wm * 64 + mi * 16 + gq * 4 + rr;
                const float vs = vsum[(size_t)row * 16 + h];
                #pragma unroll
                for (int nj = 0; nj < 4; ++nj)
                    kvp[nj] += elu1(acc[mi][nj][rr]) * vs;
            }
        #pragma unroll
        for (int nj = 0; nj < 4; ++nj) {
            kvp[nj] += __shfl_xor(kvp[nj], 16);
            kvp[nj] += __shfl_xor(kvp[nj], 32);
        }
        if (gq == 0) {
            #pragma unroll
            for (int nj = 0; nj < 4; ++nj)
                atomicAdd(&kvsum[((size_t)b * 16 + h) * 64 + nj * 16 + r], kvp[nj]);
        }
    }
}

// ---------------- Wkv[b][h][c] = sum_d kvrow[b][h][d] * W_proj[h*64+d][c] ----------------
__global__ __launch_bounds__(256) void wkv_kernel(const float* __restrict__ kvsum,
                                                  const float* __restrict__ Wproj,
                                                  float* __restrict__ wkv) {
    __shared__ float kv[64];
    const int bh = blockIdx.y;                     // 0..63
    const int c = blockIdx.x * 256 + threadIdx.x;  // 0..1023
    if (threadIdx.x < 64) kv[threadIdx.x] = kvsum[bh * 64 + threadIdx.x];
    __syncthreads();
    const int h = bh & 15;
    float s = 0.f;
    #pragma unroll 8
    for (int d = 0; d < 64; ++d)
        s += kv[d] * Wproj[(size_t)(h * 64 + d) * 1024 + c];
    wkv[(size_t)bh * 1024 + c] = s;
}

// ---------------- y[row][c] = b_proj[c] + sum_h qsum[row][h] * Wkv[b][h][c] ----------------
__global__ __launch_bounds__(256) void final_kernel(const float* __restrict__ qsum,
                                                    const float* __restrict__ wkv,
                                                    const float* __restrict__ bproj,
                                                    float* __restrict__ y) {
    __shared__ float qs[4][16];
    const int r0 = blockIdx.x * 4;                 // 4096 blocks, 4 rows each
    const int t = threadIdx.x;
    if (t < 64) qs[t >> 4][t & 15] = qsum[(size_t)(r0 + (t >> 4)) * 16 + (t & 15)];
    __syncthreads();
    const int b = r0 >> 12;
    const f32x4* wk4 = (const f32x4*)(wkv + (size_t)b * 16 * 1024);
    f32x4 bp = ((const f32x4*)bproj)[t];
    f32x4 a0 = bp, a1 = bp, a2 = bp, a3 = bp;
    #pragma unroll
    for (int h = 0; h < 16; ++h) {
        f32x4 w = wk4[h * 256 + t];
        a0 += qs[0][h] * w;
        a1 += qs[1][h] * w;
        a2 += qs[2][h] * w;
        a3 += qs[3][h] * w;
    }
    f32x4* y4 = (f32x4*)y;
    y4[(size_t)(r0 + 0) * 256 + t] = a0;
    y4[(size_t)(r0 + 1) * 256 + t] = a1;
    y4[(size_t)(r0 + 2) * 256 + t] = a2;
    y4[(size_t)(r0 + 3) * 256 + t] = a3;
}

extern "C" void kernel_launch(void* const* d_in, const int* in_sizes, int n_in,
                              void* d_out, int out_size, void* d_ws, size_t ws_size,
                              hipStream_t stream) {
    const float* x     = (const float*)d_in[0];   // [4,4096,1024]
    const float* Wqkv  = (const float*)d_in[1];   // [1024,3072]
    const float* Wproj = (const float*)d_in[2];   // [1024,1024]
    const float* bproj = (const float*)d_in[3];   // [1024]
    float* y = (float*)d_out;                     // [4,4096,1024]

    char* ws = (char*)d_ws;
    u16*   xb    = (u16*)(ws);                    // 16384*1024*2 = 33554432
    u16*   wqkt  = (u16*)(ws + 33554432);         // 2048*1024*2  =  4194304
    u16*   wvst  = (u16*)(ws + 37748736);         // 16*1024*2    =    32768
    float* vsum  = (float*)(ws + 37781504);       // 16384*16*4   =  1048576
    float* qsum  = (float*)(ws + 38830080);       // 16384*16*4   =  1048576
    float* kvsum = (float*)(ws + 39878656);       // 4*16*64*4    =    16384
    float* wkv   = (float*)(ws + 39895040);       // 4*16*1024*4  =   262144
    // total 40157184 bytes (~38.3 MiB)

    hipMemsetAsync(kvsum, 0, 4096 * sizeof(float), stream);

    cast_x_kernel<<<4096, 256, 0, stream>>>(x, xb, (MTOT * CC) / 4);
    wsum_kernel<<<1024, 256, 0, stream>>>(Wqkv, wvst);
    trans_wqk_kernel<<<dim3(64, 32), dim3(32, 8), 0, stream>>>(Wqkv, wqkt);
    vsum_kernel<<<256, 256, 0, stream>>>(xb, wvst, vsum);
    gemm_qk_kernel<<<2048, 256, 0, stream>>>(xb, wqkt, vsum, qsum, kvsum);
    wkv_kernel<<<dim3(4, 64), 256, 0, stream>>>(kvsum, Wproj, wkv);
    final_kernel<<<4096, 256, 0, stream>>>(qsum, wkv, bproj, y);
}